// Round 1
// baseline (1327.432 us; speedup 1.0000x reference)
//
#include <hip/hip_runtime.h>

typedef __attribute__((ext_vector_type(8))) short short8;
typedef __attribute__((ext_vector_type(4))) float floatx4;
typedef __attribute__((ext_vector_type(4))) unsigned short us4;

#define LDA 264   // 256 + 8 pad (ushorts)
#define LDX 72    // 64 + 8 pad  (ushorts)

__device__ inline unsigned short f2bf(float f) {
  unsigned u = __float_as_uint(f);
  u = (u + 0x7fffu + ((u >> 16) & 1u)) >> 16;   // RNE
  return (unsigned short)u;
}
__device__ inline float bf2f(unsigned short h) {
  return __uint_as_float(((unsigned)h) << 16);
}

// ---- weight prep: fp32 [k][n] -> bf16 transposed [n][k] -------------------
__global__ void prep_weights(const float* __restrict__ W0, const float* __restrict__ W1,
                             const float* __restrict__ W2, const float* __restrict__ Wqk,
                             const float* __restrict__ Wk,
                             unsigned short* __restrict__ Wt0, unsigned short* __restrict__ Wt1,
                             unsigned short* __restrict__ Wt2, unsigned short* __restrict__ Wqkt,
                             unsigned short* __restrict__ Wkt) {
  int t = blockIdx.x * blockDim.x + threadIdx.x;
  if (t < 65536) {                 // [256n][256k]
    int n = t >> 8, k = t & 255;
    Wt0[t] = f2bf(W0[k * 256 + n]);
    Wt1[t] = f2bf(W1[k * 256 + n]);
  }
  if (t < 16384) {                 // [64n][256k], W2 is [256,64]
    int n = t >> 8, k = t & 255;
    Wt2[t] = f2bf(W2[k * 64 + n]);
  }
  if (t < 2048) {                  // [32n][64k], Wqk/Wk are [64,32]
    int n = t >> 6, k = t & 63;
    Wqkt[t] = f2bf(Wqk[k * 32 + n]);
    Wkt[t]  = f2bf(Wk[k * 32 + n]);
  }
}

// ---- 256->256 layer with relu: dst = relu(src @ W), all tiles [64 x 256] ---
__device__ inline void layer256(const unsigned short* src, unsigned short* dst,
                                const unsigned short* __restrict__ Wt,
                                int wave, int col, int quad) {
  floatx4 acc[4][4];
#pragma unroll
  for (int i = 0; i < 4; ++i)
#pragma unroll
    for (int j = 0; j < 4; ++j) acc[i][j] = (floatx4)0.0f;
  const int nbase = wave * 64;
#pragma unroll
  for (int ks = 0; ks < 8; ++ks) {
    const int k0 = ks * 32 + quad * 8;
    short8 bf[4], af[4];
#pragma unroll
    for (int nt = 0; nt < 4; ++nt)
      bf[nt] = *(const short8*)(Wt + (nbase + nt * 16 + col) * 256 + k0);
#pragma unroll
    for (int mt = 0; mt < 4; ++mt)
      af[mt] = *(const short8*)(src + (mt * 16 + col) * LDA + k0);
#pragma unroll
    for (int mt = 0; mt < 4; ++mt)
#pragma unroll
      for (int nt = 0; nt < 4; ++nt)
        acc[mt][nt] = __builtin_amdgcn_mfma_f32_16x16x32_bf16(af[mt], bf[nt], acc[mt][nt], 0, 0, 0);
  }
#pragma unroll
  for (int mt = 0; mt < 4; ++mt)
#pragma unroll
    for (int nt = 0; nt < 4; ++nt) {
      const int c = nbase + nt * 16 + col;
#pragma unroll
      for (int r = 0; r < 4; ++r) {
        float v = acc[mt][nt][r];
        v = v > 0.0f ? v : 0.0f;
        dst[(mt * 16 + quad * 4 + r) * LDA + c] = f2bf(v);
      }
    }
}

// ---- 256->64 layer (no relu): x[64x64] bf16 into xdst (stride LDX) --------
__device__ inline void layer64(const unsigned short* src, unsigned short* xdst,
                               const unsigned short* __restrict__ Wt2,
                               int wave, int col, int quad) {
  floatx4 acc[4];
#pragma unroll
  for (int nt = 0; nt < 4; ++nt) acc[nt] = (floatx4)0.0f;
#pragma unroll
  for (int ks = 0; ks < 8; ++ks) {
    const int k0 = ks * 32 + quad * 8;
    short8 a = *(const short8*)(src + (wave * 16 + col) * LDA + k0);
#pragma unroll
    for (int nt = 0; nt < 4; ++nt) {
      short8 b = *(const short8*)(Wt2 + (nt * 16 + col) * 256 + k0);
      acc[nt] = __builtin_amdgcn_mfma_f32_16x16x32_bf16(a, b, acc[nt], 0, 0, 0);
    }
  }
#pragma unroll
  for (int nt = 0; nt < 4; ++nt)
#pragma unroll
    for (int r = 0; r < 4; ++r)
      xdst[(wave * 16 + quad * 4 + r) * LDX + nt * 16 + col] = f2bf(acc[nt][r]);
}

// ---- x[64x64] @ Wh[64x32] -> [64x32]: wave w owns rows 16w..16w+15 --------
__device__ inline void qkgemm(const unsigned short* x, const unsigned short* __restrict__ Wqt,
                              floatx4 acc[2], int wave, int col, int quad) {
  acc[0] = (floatx4)0.0f;
  acc[1] = (floatx4)0.0f;
#pragma unroll
  for (int ks = 0; ks < 2; ++ks) {
    const int k0 = ks * 32 + quad * 8;
    short8 a = *(const short8*)(x + (wave * 16 + col) * LDX + k0);
#pragma unroll
    for (int nt = 0; nt < 2; ++nt) {
      short8 b = *(const short8*)(Wqt + (nt * 16 + col) * 64 + k0);
      acc[nt] = __builtin_amdgcn_mfma_f32_16x16x32_bf16(a, b, acc[nt], 0, 0, 0);
    }
  }
}

template <bool IS_SRC>
__global__ __launch_bounds__(256, 2) void mlp_fused(
    const float* __restrict__ attr, const float* __restrict__ ppr_scores,
    const int* __restrict__ ppr_idx,
    const unsigned short* __restrict__ Wt0, const unsigned short* __restrict__ Wt1,
    const unsigned short* __restrict__ Wt2, const unsigned short* __restrict__ Wqt,
    float* __restrict__ qbuf, float* __restrict__ out) {
  __shared__ alignas(16) unsigned short bufA[64 * LDA];
  __shared__ alignas(16) unsigned short bufB[64 * LDA];
  __shared__ float escale[64];
  __shared__ int gid[64];

  const int t = threadIdx.x;
  const int lane = t & 63;
  const int wave = t >> 6;
  const int col = lane & 15;
  const int quad = lane >> 4;
  const long rowbase = (long)blockIdx.x * 64;

  // stage attr tile [64 x 256] fp32 -> bf16 LDS (coalesced float4 loads)
#pragma unroll
  for (int it = 0; it < 16; ++it) {
    int flat = it * 1024 + t * 4;
    int row = flat >> 8, c = flat & 255;
    const float4 v = *(const float4*)(attr + (rowbase + row) * 256 + c);
    us4 p;
    p.x = f2bf(v.x); p.y = f2bf(v.y); p.z = f2bf(v.z); p.w = f2bf(v.w);
    *(us4*)(bufA + row * LDA + c) = p;
  }
  if (!IS_SRC && t < 64) gid[t] = ppr_idx[rowbase + t];
  __syncthreads();

  layer256(bufA, bufB, Wt0, wave, col, quad);   // h1 = relu(X@W0)
  __syncthreads();
  layer256(bufB, bufA, Wt1, wave, col, quad);   // h2 = relu(h1@W1)
  __syncthreads();
  layer64(bufA, bufB, Wt2, wave, col, quad);    // x = h2@W2  (bf16 in bufB, stride LDX)
  __syncthreads();

  floatx4 acc[2];
  qkgemm(bufB, Wqt, acc, wave, col, quad);      // q or k, [64 x 32], C-layout

  if (IS_SRC) {
    // write q [E,32] fp32
#pragma unroll
    for (int nt = 0; nt < 2; ++nt)
#pragma unroll
      for (int r = 0; r < 4; ++r) {
        long erow = rowbase + wave * 16 + quad * 4 + r;
        qbuf[erow * 32 + nt * 16 + col] = acc[nt][r];
      }
  } else {
    // e = sigmoid(q . k) * ppr
    float part[4] = {0.f, 0.f, 0.f, 0.f};
#pragma unroll
    for (int nt = 0; nt < 2; ++nt)
#pragma unroll
      for (int r = 0; r < 4; ++r) {
        long erow = rowbase + wave * 16 + quad * 4 + r;
        part[r] += qbuf[erow * 32 + nt * 16 + col] * acc[nt][r];
      }
#pragma unroll
    for (int r = 0; r < 4; ++r) {
      float s = part[r];
      s += __shfl_xor(s, 1);
      s += __shfl_xor(s, 2);
      s += __shfl_xor(s, 4);
      s += __shfl_xor(s, 8);
      if (col == 0) {
        int lrow = wave * 16 + quad * 4 + r;
        float sig = 1.0f / (1.0f + __expf(-s));
        escale[lrow] = sig * ppr_scores[rowbase + lrow];
      }
    }
    __syncthreads();
    // scatter: run-length-merged atomics (ppr_idx sorted)
    const int c = t & 63;
    const int r0 = (t >> 6) * 16;
    float run = 0.0f;
    int cur = gid[r0];
#pragma unroll
    for (int i = 0; i < 16; ++i) {
      int row = r0 + i;
      int g = gid[row];
      float v = bf2f(bufB[row * LDX + c]) * escale[row];
      if (g != cur) {
        atomicAdd(out + (long)cur * 64 + c, run);
        run = 0.0f;
        cur = g;
      }
      run += v;
    }
    atomicAdd(out + (long)cur * 64 + c, run);
  }
}

extern "C" void kernel_launch(void* const* d_in, const int* in_sizes, int n_in,
                              void* d_out, int out_size, void* d_ws, size_t ws_size,
                              hipStream_t stream) {
  const float* src_attr = (const float*)d_in[0];
  const float* nbr_attr = (const float*)d_in[1];
  const float* ppr      = (const float*)d_in[2];
  const int*   pidx     = (const int*)d_in[3];
  // d_in[4] = neighbor_idx: unused by the reference
  const float* W0  = (const float*)d_in[5];
  const float* W1  = (const float*)d_in[6];
  const float* W2  = (const float*)d_in[7];
  const float* Wqk = (const float*)d_in[8];
  const float* Wk  = (const float*)d_in[9];
  float* out = (float*)d_out;
  const int E = in_sizes[2];      // 400000

  char* ws = (char*)d_ws;
  float* qbuf = (float*)ws;
  size_t off = (size_t)E * 32 * sizeof(float);
  unsigned short* Wt0  = (unsigned short*)(ws + off); off += 65536 * 2;
  unsigned short* Wt1  = (unsigned short*)(ws + off); off += 65536 * 2;
  unsigned short* Wt2  = (unsigned short*)(ws + off); off += 16384 * 2;
  unsigned short* Wqkt = (unsigned short*)(ws + off); off += 2048 * 2;
  unsigned short* Wkt  = (unsigned short*)(ws + off); off += 2048 * 2;

  hipMemsetAsync(d_out, 0, (size_t)out_size * sizeof(float), stream);
  prep_weights<<<256, 256, 0, stream>>>(W0, W1, W2, Wqk, Wk, Wt0, Wt1, Wt2, Wqkt, Wkt);

  const int blocks = E / 64;  // E = 400000 -> 6250
  mlp_fused<true><<<blocks, 256, 0, stream>>>(src_attr, ppr, pidx, Wt0, Wt1, Wt2, Wqkt, qbuf, out);
  mlp_fused<false><<<blocks, 256, 0, stream>>>(nbr_attr, ppr, pidx, Wt0, Wt1, Wt2, Wkt, qbuf, out);
}